// Round 6
// baseline (316.374 us; speedup 1.0000x reference)
//
#include <hip/hip_runtime.h>

#define NAG 256
#define HID 128
#define ACT 5
#define NH 4
#define DD 144      // concat dim
#define EE 576      // embed dim
#define HDIM 144    // per-head dim
#define CMAX 32     // fast-path neighbor cap (LDS-resident c x c scores)

// ===========================================================================
// Generic 8x64 GEMM tile core, ONE-WAVE (64-thread) block, DEPTH-4 pipelined.
//   out[8 x 64] = A[8 x K] @ W[K x 64-col-tile]  (+ bias / + rowscale*rowbias)
// Thread micro-tile: 2 rows x 4 cols. W loads are software-pipelined 4 groups
// ahead (16 float4 in flight per thread) so the loop is VALU-issue-bound,
// not load-latency-bound (round-5 counters: depth-1 was ~330 GB/s effective,
// 10% VALUBusy). A-tile staged once in LDS (single __syncthreads).
// Requires K % 16 == 0 (KF multiple of 4).
// ===========================================================================
#define STEP4(acc, a) do { \
    acc.x += (a).x*wc0.x + (a).y*wc1.x + (a).z*wc2.x + (a).w*wc3.x; \
    acc.y += (a).x*wc0.y + (a).y*wc1.y + (a).z*wc2.y + (a).w*wc3.y; \
    acc.z += (a).x*wc0.z + (a).y*wc1.z + (a).z*wc2.z + (a).w*wc3.z; \
    acc.w += (a).x*wc0.w + (a).y*wc1.w + (a).z*wc2.w + (a).w*wc3.w; } while (0)

__device__ __forceinline__ void gemm8x64(
    const float* __restrict__ A,     // row-block start: [8][K], row stride lda
    const float* __restrict__ Wt,    // W + col-tile base cb: [K][ldw]
    const float* __restrict__ bv,    // bias + cb (or nullptr)
    const float* __restrict__ rs,    // rowscale (cnt) + row-block base (or nullptr)
    const float* __restrict__ rb,    // row-scaled bias + cb (used with rs)
    float* __restrict__ outp,        // out + rowbase*ldo + cb
    int K, int lda, int ldw, int ldo, int nvalid, float scale,
    int tid, float* __restrict__ Asm)
{
    const int lsa = K + 4;
    const int KF = K >> 2;
    for (int idx = tid; idx < 8 * KF; idx += 64) {
        int r = idx / KF, f = idx - r * KF;
        *((float4*)&Asm[r * lsa + f * 4]) =
            *(const float4*)(A + (size_t)r * lda + f * 4);
    }
    __syncthreads();
    const int cg = tid & 15, rg = tid >> 4;
    const int co = cg * 4;
    const bool cok = (co + 4 <= nvalid);
    const float* Wp = Wt + (cok ? co : 0);
    float4 acc0 = {0.f, 0.f, 0.f, 0.f}, acc1 = {0.f, 0.f, 0.f, 0.f};
    // depth-4 register pipeline: wb[p] holds W rows 4g..4g+3 for group g=gb+p
    float4 wb[4][4];
    #pragma unroll
    for (int p = 0; p < 4; ++p) {
        const float* Wg = Wp + (size_t)(4 * p) * ldw;
        wb[p][0] = *(const float4*)(Wg);
        wb[p][1] = *(const float4*)(Wg + (size_t)ldw);
        wb[p][2] = *(const float4*)(Wg + 2 * (size_t)ldw);
        wb[p][3] = *(const float4*)(Wg + 3 * (size_t)ldw);
    }
    const float* Asr = Asm + rg * 2 * lsa;
    for (int gb = 0; gb < KF; gb += 4) {
        #pragma unroll
        for (int u = 0; u < 4; ++u) {
            const int g = gb + u;
            float4 a0 = *((const float4*)(Asr + g * 4));
            float4 a1 = *((const float4*)(Asr + lsa + g * 4));
            float4 wc0 = wb[u][0], wc1 = wb[u][1], wc2 = wb[u][2], wc3 = wb[u][3];
            STEP4(acc0, a0);
            STEP4(acc1, a1);
            const int gn = g + 4;
            if (gn < KF) {                       // wave-uniform
                const float* Wg = Wp + (size_t)(4 * gn) * ldw;
                wb[u][0] = *(const float4*)(Wg);
                wb[u][1] = *(const float4*)(Wg + (size_t)ldw);
                wb[u][2] = *(const float4*)(Wg + 2 * (size_t)ldw);
                wb[u][3] = *(const float4*)(Wg + 3 * (size_t)ldw);
            }
        }
    }
    if (cok) {
        float4 add0 = {0.f, 0.f, 0.f, 0.f}, add1 = {0.f, 0.f, 0.f, 0.f};
        if (bv) {
            float4 b = *(const float4*)(bv + co);
            add0 = b; add1 = b;
        }
        if (rs) {
            float4 b = *(const float4*)(rb + co);
            float r0 = rs[rg * 2], r1 = rs[rg * 2 + 1];
            add0.x += r0 * b.x; add0.y += r0 * b.y; add0.z += r0 * b.z; add0.w += r0 * b.w;
            add1.x += r1 * b.x; add1.y += r1 * b.y; add1.z += r1 * b.z; add1.w += r1 * b.w;
        }
        float* o0 = outp + (size_t)(rg * 2) * ldo + co;
        float* o1 = o0 + ldo;
        float4 v0 = { acc0.x * scale + add0.x, acc0.y * scale + add0.y,
                      acc0.z * scale + add0.z, acc0.w * scale + add0.w };
        float4 v1 = { acc1.x * scale + add1.x, acc1.y * scale + add1.y,
                      acc1.z * scale + add1.z, acc1.w * scale + add1.w };
        *(float4*)o0 = v0;
        *(float4*)o1 = v1;
    }
}

// ---------------------------------------------------------------------------
// k_enc (32 blocks x 256): C = concat(hidden @ W_enc + b_enc, action)
// ---------------------------------------------------------------------------
__global__ __launch_bounds__(256) void k_enc(
    const float* __restrict__ hidden, const float* __restrict__ action,
    const float* __restrict__ W_enc, const float* __restrict__ b_enc,
    float* __restrict__ C)
{
    __shared__ float Hs[8 * 132];
    __shared__ float We[2048];
    const int mb = blockIdx.x, tid = threadIdx.x;
    {
        int r = tid >> 5, kq = tid & 31;
        *((float4*)&Hs[r * 132 + kq * 4]) =
            *(const float4*)(hidden + (size_t)(mb * 8 + r) * HID + kq * 4);
        float4 a4 = *(const float4*)(action + (size_t)(mb * 8 + r) * HID + kq * 4);
        *((float4*)(C + (size_t)(mb * 8 + r) * DD + 16 + kq * 4)) = a4;
        *((float4*)&We[tid * 4])        = *(const float4*)(W_enc + tid * 4);
        *((float4*)&We[1024 + tid * 4]) = *(const float4*)(W_enc + 1024 + tid * 4);
    }
    __syncthreads();
    if (tid < 128) {
        int r = tid >> 4, o = tid & 15;
        float acc = 0.f;
        #pragma unroll 8
        for (int d = 0; d < HID; ++d) acc += Hs[r * 132 + d] * We[d * 16 + o];
        C[(size_t)(mb * 8 + r) * DD + o] = acc + b_enc[o];
    }
}

// ---------------------------------------------------------------------------
// k_t3 (grid 32x9x3, 64 thr): T_z = C @ Wz + bz   (K=144)
// ---------------------------------------------------------------------------
__global__ __launch_bounds__(64) void k_t3(
    const float* __restrict__ C,
    const float* __restrict__ Wq, const float* __restrict__ bq,
    const float* __restrict__ Wk, const float* __restrict__ bk,
    const float* __restrict__ Wv, const float* __restrict__ bv,
    float* __restrict__ Tq, float* __restrict__ Tk, float* __restrict__ Tv)
{
    __shared__ float Asm[8 * 148];
    const int z = blockIdx.z;
    const float* W = (z == 0) ? Wq : (z == 1) ? Wk : Wv;
    const float* b = (z == 0) ? bq : (z == 1) ? bk : bv;
    float*       T = (z == 0) ? Tq : (z == 1) ? Tk : Tv;
    const int rbase = blockIdx.x * 8, cb = blockIdx.y * 64;
    gemm8x64(C + (size_t)rbase * DD, W + cb, b + cb, nullptr, nullptr,
             T + (size_t)rbase * EE + cb, DD, DD, EE, EE, 64, 1.f,
             threadIdx.x, Asm);
}

// ---------------------------------------------------------------------------
// k_qkv3 (grid 32x9x3, 64 thr): {q,k,v} = T_z @ Wiz + biz   (K=576)
// ---------------------------------------------------------------------------
__global__ __launch_bounds__(64) void k_qkv3(
    const float* __restrict__ Tq, const float* __restrict__ Tk, const float* __restrict__ Tv,
    const float* __restrict__ Wiq, const float* __restrict__ biq,
    const float* __restrict__ Wik, const float* __restrict__ bik,
    const float* __restrict__ Wiv, const float* __restrict__ biv,
    float* __restrict__ q, float* __restrict__ kb, float* __restrict__ v)
{
    __shared__ float Asm[8 * 580];
    const int z = blockIdx.z;
    const float* A = (z == 0) ? Tq  : (z == 1) ? Tk  : Tv;
    const float* W = (z == 0) ? Wiq : (z == 1) ? Wik : Wiv;
    const float* b = (z == 0) ? biq : (z == 1) ? bik : biv;
    float*       o = (z == 0) ? q   : (z == 1) ? kb  : v;
    const int rbase = blockIdx.x * 8, cb = blockIdx.y * 64;
    gemm8x64(A + (size_t)rbase * EE, W + cb, b + cb, nullptr, nullptr,
             o + (size_t)rbase * EE + cb, EE, EE, EE, EE, 64, 1.f,
             threadIdx.x, Asm);
}

// ---------------------------------------------------------------------------
// k_score (grid 32x4x4, 64 thr): S[h][j][k] = (q_j . k_k)/12  for ALL pairs.
// ---------------------------------------------------------------------------
#define DOT4(a, b) ((a).x*(b).x + (a).y*(b).y + (a).z*(b).z + (a).w*(b).w)

__global__ __launch_bounds__(64) void k_score(
    const float* __restrict__ q, const float* __restrict__ kmat,
    float* __restrict__ S)
{
    __shared__ float Aq[8 * 148];
    __shared__ float Bk[64 * 148];
    const int tid = threadIdx.x;
    const int jb = blockIdx.x * 8, kbb = blockIdx.y * 64, h = blockIdx.z;
    const float* Ap = q    + (size_t)jb  * EE + h * HDIM;
    const float* Bp = kmat + (size_t)kbb * EE + h * HDIM;
    for (int idx = tid; idx < 8 * 36; idx += 64) {
        int r = idx / 36, f = idx - r * 36;
        *((float4*)&Aq[r * 148 + f * 4]) = *(const float4*)(Ap + (size_t)r * EE + f * 4);
    }
    for (int idx = tid; idx < 64 * 36; idx += 64) {
        int r = idx / 36, f = idx - r * 36;
        *((float4*)&Bk[r * 148 + f * 4]) = *(const float4*)(Bp + (size_t)r * EE + f * 4);
    }
    __syncthreads();
    const int cg = tid & 15, rg = tid >> 4;
    const int c0 = cg * 4;
    float4 acc0 = {0.f, 0.f, 0.f, 0.f}, acc1 = {0.f, 0.f, 0.f, 0.f};
    const float* A0 = Aq + (rg * 2) * 148;
    const float* A1 = A0 + 148;
    const float* B0 = Bk + (c0 + 0) * 148;
    const float* B1 = Bk + (c0 + 1) * 148;
    const float* B2 = Bk + (c0 + 2) * 148;
    const float* B3 = Bk + (c0 + 3) * 148;
    for (int g = 0; g < 36; ++g) {
        float4 a0 = *((const float4*)(A0 + g * 4));
        float4 a1 = *((const float4*)(A1 + g * 4));
        float4 b0 = *((const float4*)(B0 + g * 4));
        float4 b1 = *((const float4*)(B1 + g * 4));
        float4 b2 = *((const float4*)(B2 + g * 4));
        float4 b3 = *((const float4*)(B3 + g * 4));
        acc0.x += DOT4(a0, b0); acc0.y += DOT4(a0, b1);
        acc0.z += DOT4(a0, b2); acc0.w += DOT4(a0, b3);
        acc1.x += DOT4(a1, b0); acc1.y += DOT4(a1, b1);
        acc1.z += DOT4(a1, b2); acc1.w += DOT4(a1, b3);
    }
    const float SC = 1.0f / 12.0f;
    float* Sp = S + ((size_t)(h * NAG + jb + rg * 2)) * NAG + kbb + c0;
    float4 o0 = { acc0.x * SC, acc0.y * SC, acc0.z * SC, acc0.w * SC };
    float4 o1 = { acc1.x * SC, acc1.y * SC, acc1.z * SC, acc1.w * SC };
    *(float4*)Sp = o0;
    *(float4*)(Sp + NAG) = o1;
}

// ---------------------------------------------------------------------------
// k_agent (grid 256 x 256 thr): neighbor list -> gather S -> softmax ->
// column-sum weights -> ctx = sum w*v.
// ---------------------------------------------------------------------------
__global__ __launch_bounds__(256) void k_agent(
    const int* __restrict__ state, const float* __restrict__ S,
    const float* __restrict__ v,
    float* __restrict__ ctxsum, float* __restrict__ cnt)
{
    __shared__ int lst[NAG];
    __shared__ int cnt_s;
    __shared__ float w4[NH][NAG];
    __shared__ float Sl[NH][CMAX][CMAX + 1];
    const int i = blockIdx.x, tid = threadIdx.x;
    if (tid == 0) cnt_s = 0;
    __syncthreads();
    {
        int xi = state[2 * i], yi = state[2 * i + 1];
        int xj = state[2 * tid], yj = state[2 * tid + 1];
        int dx = xi - xj; if (dx < 0) dx = -dx;
        int dy = yi - yj; if (dy < 0) dy = -dy;
        if (tid > i && dx <= 4 && dy <= 2) {
            int p = atomicAdd(&cnt_s, 1);
            lst[p] = tid;
        }
    }
    __syncthreads();
    const int c = cnt_s;                    // block-uniform
    if (tid == 0) cnt[i] = (float)c;
    if (c == 0) {
        for (int e = tid; e < EE; e += 256) ctxsum[(size_t)i * EE + e] = 0.f;
        return;
    }
    if (c <= CMAX) {
        for (int idx = tid; idx < NH * c * c; idx += 256) {
            int h = idx / (c * c), rem = idx - h * c * c;
            int jj = rem / c, kk = rem - jj * c;
            Sl[h][jj][kk] = S[((size_t)(h * NAG + lst[jj])) * NAG + lst[kk]];
        }
        __syncthreads();
        if (tid < NH * c) {
            int h = tid / c, jj = tid - h * c;
            float m = -1e30f;
            for (int kk = 0; kk < c; ++kk) m = fmaxf(m, Sl[h][jj][kk]);
            float zz = 0.f;
            for (int kk = 0; kk < c; ++kk) {
                float e = __expf(Sl[h][jj][kk] - m);
                Sl[h][jj][kk] = e;
                zz += e;
            }
            float inv = 1.f / fmaxf(zz, 1e-9f);
            for (int kk = 0; kk < c; ++kk) Sl[h][jj][kk] *= inv;
        }
        __syncthreads();
        if (tid < NH * c) {
            int h = tid / c, kk = tid - h * c;
            float s = 0.f;
            for (int jj = 0; jj < c; ++jj) s += Sl[h][jj][kk];
            w4[h][kk] = s;
        }
        __syncthreads();
    } else {
        for (int idx = tid; idx < NH * c; idx += 256) w4[idx / c][idx % c] = 0.f;
        __syncthreads();
        for (int t = tid; t < NH * c; t += 256) {
            int h = t / c, jj = t - h * c;
            const float* Srow = S + ((size_t)(h * NAG + lst[jj])) * NAG;
            float m = -1e30f;
            for (int kk = 0; kk < c; ++kk) m = fmaxf(m, Srow[lst[kk]]);
            float zz = 0.f;
            for (int kk = 0; kk < c; ++kk) zz += __expf(Srow[lst[kk]] - m);
            float inv = 1.f / fmaxf(zz, 1e-9f);
            for (int kk = 0; kk < c; ++kk)
                atomicAdd(&w4[h][kk], __expf(Srow[lst[kk]] - m) * inv);
        }
        __syncthreads();
    }
    for (int e = tid; e < EE; e += 256) {
        int h = e / HDIM;
        float a0 = 0.f, a1 = 0.f;
        int t = 0;
        for (; t + 1 < c; t += 2) {
            a0 += w4[h][t] * v[(size_t)lst[t] * EE + e];
            a1 += w4[h][t + 1] * v[(size_t)lst[t + 1] * EE + e];
        }
        if (t < c) a0 += w4[h][t] * v[(size_t)lst[t] * EE + e];
        ctxsum[(size_t)i * EE + e] = a0 + a1;
    }
}

// ---------------------------------------------------------------------------
// k_g (grid 32x9, 64 thr): g = ctx @ Wo + cnt*bo   (K=576)
// ---------------------------------------------------------------------------
__global__ __launch_bounds__(64) void k_g(
    const float* __restrict__ ctx, const float* __restrict__ Wo,
    const float* __restrict__ bo, const float* __restrict__ cnt,
    float* __restrict__ g)
{
    __shared__ float Asm[8 * 580];
    const int rbase = blockIdx.x * 8, cb = blockIdx.y * 64;
    gemm8x64(ctx + (size_t)rbase * EE, Wo + cb, nullptr, cnt + rbase, bo + cb,
             g + (size_t)rbase * EE + cb, EE, EE, EE, EE, 64, 1.f,
             threadIdx.x, Asm);
}

// ---------------------------------------------------------------------------
// k_h (grid 32x3, 64 thr): hbuf = g @ W_O   (K=576, N=144)
// ---------------------------------------------------------------------------
__global__ __launch_bounds__(64) void k_h(
    const float* __restrict__ g, const float* __restrict__ W_O,
    float* __restrict__ hbuf)
{
    __shared__ float Asm[8 * 580];
    const int rbase = blockIdx.x * 8, cb = blockIdx.y * 64;
    gemm8x64(g + (size_t)rbase * EE, W_O + cb, nullptr, nullptr, nullptr,
             hbuf + (size_t)rbase * DD + cb, EE, EE, DD, DD, DD - cb, 1.f,
             threadIdx.x, Asm);
}

// ---------------------------------------------------------------------------
// k_head (grid 64 x 256): dueling head, one wave per agent.
// ---------------------------------------------------------------------------
__global__ __launch_bounds__(256) void k_head(
    const float* __restrict__ hbuf,
    const float* __restrict__ W_val, const float* __restrict__ b_val,
    const float* __restrict__ W_adv, const float* __restrict__ b_adv,
    float* __restrict__ out)
{
    const int ag = blockIdx.x * 4 + (threadIdx.x >> 6);
    const int lane = threadIdx.x & 63;
    const float* hp = hbuf + (size_t)ag * DD;
    float h0 = hp[lane], h1 = hp[lane + 64];
    float h2 = (lane < 16) ? hp[lane + 128] : 0.f;
    float red[6];
    for (int o = 0; o < 6; ++o) {
        float p;
        if (o < 5) {
            p = h0 * W_adv[lane * ACT + o] + h1 * W_adv[(lane + 64) * ACT + o];
            if (lane < 16) p += h2 * W_adv[(lane + 128) * ACT + o];
        } else {
            p = h0 * W_val[lane] + h1 * W_val[lane + 64];
            if (lane < 16) p += h2 * W_val[lane + 128];
        }
        for (int off = 32; off; off >>= 1) p += __shfl_xor(p, off);
        red[o] = p;
    }
    if (lane == 0) {
        float a[ACT], mean = 0.f;
        for (int o = 0; o < ACT; ++o) { a[o] = red[o] + b_adv[o]; mean += a[o]; }
        mean *= (1.0f / ACT);
        float V = red[5] + b_val[0];
        for (int o = 0; o < ACT; ++o) out[ag * ACT + o] = V + a[o] - mean;
    }
}

// ---------------------------------------------------------------------------
extern "C" void kernel_launch(void* const* d_in, const int* in_sizes, int n_in,
                              void* d_out, int out_size, void* d_ws, size_t ws_size,
                              hipStream_t stream)
{
    const float* hidden = (const float*)d_in[0];
    const float* action = (const float*)d_in[1];
    const int*   state  = (const int*)d_in[2];
    const float* W_enc  = (const float*)d_in[3];
    const float* b_enc  = (const float*)d_in[4];
    const float* Wq     = (const float*)d_in[5];
    const float* bq     = (const float*)d_in[6];
    const float* Wk     = (const float*)d_in[7];
    const float* bk     = (const float*)d_in[8];
    const float* Wv     = (const float*)d_in[9];
    const float* bv     = (const float*)d_in[10];
    const float* Wiq    = (const float*)d_in[11];
    const float* biq    = (const float*)d_in[12];
    const float* Wik    = (const float*)d_in[13];
    const float* bik    = (const float*)d_in[14];
    const float* Wiv    = (const float*)d_in[15];
    const float* biv    = (const float*)d_in[16];
    const float* Wo     = (const float*)d_in[17];
    const float* bo     = (const float*)d_in[18];
    const float* W_O    = (const float*)d_in[19];
    const float* W_val  = (const float*)d_in[20];
    const float* b_val  = (const float*)d_in[21];
    const float* W_adv  = (const float*)d_in[22];
    const float* b_adv  = (const float*)d_in[23];
    float* outp = (float*)d_out;

    float* ws = (float*)d_ws;
    float* C    = ws;                        // 256*144   = 36864
    float* Tq   = C    + NAG * DD;           // 256*576   = 147456 each
    float* Tk   = Tq   + NAG * EE;
    float* Tv   = Tk   + NAG * EE;
    float* q    = Tv   + NAG * EE;
    float* kb   = q    + NAG * EE;
    float* v    = kb   + NAG * EE;
    float* S    = v    + NAG * EE;           // 4*256*256 = 262144
    float* ctx  = S    + NH * NAG * NAG;
    float* g    = ctx  + NAG * EE;
    float* hbuf = g    + NAG * EE;           // 256*144
    float* cnt  = hbuf + NAG * DD;           // 256
    // total ~6.1 MB

    k_enc<<<32, 256, 0, stream>>>(hidden, action, W_enc, b_enc, C);
    k_t3<<<dim3(32, 9, 3), 64, 0, stream>>>(C, Wq, bq, Wk, bk, Wv, bv, Tq, Tk, Tv);
    k_qkv3<<<dim3(32, 9, 3), 64, 0, stream>>>(Tq, Tk, Tv, Wiq, biq, Wik, bik,
                                              Wiv, biv, q, kb, v);
    k_score<<<dim3(32, 4, 4), 64, 0, stream>>>(q, kb, S);
    k_agent<<<NAG, 256, 0, stream>>>(state, S, v, ctx, cnt);
    k_g<<<dim3(32, 9), 64, 0, stream>>>(ctx, Wo, bo, cnt, g);
    k_h<<<dim3(32, 3), 64, 0, stream>>>(g, W_O, hbuf);
    k_head<<<64, 256, 0, stream>>>(hbuf, W_val, b_val, W_adv, b_adv, outp);
}

// Round 7
// 191.581 us; speedup vs baseline: 1.6514x; 1.6514x over previous
//
#include <hip/hip_runtime.h>

#define NAG 256
#define HID 128
#define ACT 5
#define NH 4
#define DD 144      // concat dim
#define EE 576      // embed dim
#define HDIM 144    // per-head dim
#define CMAX 32     // fast-path neighbor cap (LDS-resident c x c scores)

// ===========================================================================
// Split-K 8x64 GEMM tile, 256-thread (4-wave) block.
//   out[8 x 64] = A[8 x K] @ W[K x 64-tile]  (+ bias and/or rowscale*rowbias)
// Wave w computes the K/4 slice with the PROVEN round-5 depth-1 loop
// (2-row x 4-col thread micro-tile, ~88 VGPR, no spills); 4-wave LDS reduce.
// Latency hiding comes from TLP: 4 waves/block x ~3.4 blocks/CU ~= 3.4
// waves/SIMD (round 5 had 0.85 -> 10% VALUBusy; round 6 ILP attempt spilled:
// VGPR=256, 101 MB scratch writes).
// Requires K % 16 == 0. sm must hold >= max(8*(K+4), 2048) floats.
// ===========================================================================
#define STEP4(acc, a) do { \
    acc.x += (a).x*wc0.x + (a).y*wc1.x + (a).z*wc2.x + (a).w*wc3.x; \
    acc.y += (a).x*wc0.y + (a).y*wc1.y + (a).z*wc2.y + (a).w*wc3.y; \
    acc.z += (a).x*wc0.z + (a).y*wc1.z + (a).z*wc2.z + (a).w*wc3.z; \
    acc.w += (a).x*wc0.w + (a).y*wc1.w + (a).z*wc2.w + (a).w*wc3.w; } while (0)

__device__ __forceinline__ void gemm8x64_sk(
    const float* __restrict__ A,     // row-block start: [8][K], row stride lda
    const float* __restrict__ Wt,    // W + col-tile base cb: [K][ldw]
    const float* __restrict__ bv,    // bias + cb (or nullptr)
    const float* __restrict__ rs,    // rowscale (cnt) + row-block base (or nullptr)
    const float* __restrict__ rb,    // row-scaled bias + cb (used with rs)
    float* __restrict__ outp,        // out + rowbase*ldo + cb
    int K, int lda, int ldw, int ldo, int nvalid,
    int tid, float* __restrict__ sm)
{
    const int lsa = K + 4;
    const int KF4 = K >> 2;
    for (int idx = tid; idx < 8 * KF4; idx += 256) {
        int r = idx / KF4, f = idx - r * KF4;
        *((float4*)&sm[r * lsa + f * 4]) =
            *(const float4*)(A + (size_t)r * lda + f * 4);
    }
    __syncthreads();
    const int wave = tid >> 6, lane = tid & 63;
    const int cg = lane & 15, rg = lane >> 4;
    const int co = cg * 4;
    const bool cok = (co + 4 <= nvalid);
    const int Kq = K >> 2;                   // per-wave K slice
    const int kbase = wave * Kq;
    const float* Wp = Wt + (size_t)kbase * ldw + (cok ? co : 0);
    float4 acc0 = {0.f, 0.f, 0.f, 0.f}, acc1 = {0.f, 0.f, 0.f, 0.f};
    float4 wc0, wc1, wc2, wc3;
    wc0 = *(const float4*)(Wp);
    wc1 = *(const float4*)(Wp + (size_t)ldw);
    wc2 = *(const float4*)(Wp + 2 * (size_t)ldw);
    wc3 = *(const float4*)(Wp + 3 * (size_t)ldw);
    const float* Asr = sm + (rg * 2) * lsa + kbase;
    const int NG = Kq >> 2;
    for (int g = 0; g < NG; ++g) {
        float4 nx0, nx1, nx2, nx3;
        if (g + 1 < NG) {                    // wave-uniform
            const float* Wn = Wp + (size_t)(4 * (g + 1)) * ldw;
            nx0 = *(const float4*)(Wn);
            nx1 = *(const float4*)(Wn + (size_t)ldw);
            nx2 = *(const float4*)(Wn + 2 * (size_t)ldw);
            nx3 = *(const float4*)(Wn + 3 * (size_t)ldw);
        }
        float4 a0 = *((const float4*)(Asr + g * 4));
        float4 a1 = *((const float4*)(Asr + lsa + g * 4));
        STEP4(acc0, a0);
        STEP4(acc1, a1);
        wc0 = nx0; wc1 = nx1; wc2 = nx2; wc3 = nx3;
    }
    __syncthreads();                         // all waves done reading A
    float* red = sm;                         // alias: 4*8*64 = 2048 floats
    *((float4*)&red[wave * 512 + (rg * 2 + 0) * 64 + co]) = acc0;
    *((float4*)&red[wave * 512 + (rg * 2 + 1) * 64 + co]) = acc1;
    __syncthreads();
    #pragma unroll
    for (int qq = 0; qq < 2; ++qq) {
        int idx = tid + qq * 256;            // = r*64 + cl
        int r = idx >> 6, cl = idx & 63;
        if (cl < nvalid) {
            float s = red[idx] + red[512 + idx] + red[1024 + idx] + red[1536 + idx];
            float add = bv ? bv[cl] : 0.f;
            if (rs) add += rs[r] * rb[cl];
            outp[(size_t)r * ldo + cl] = s + add;
        }
    }
}

// ---------------------------------------------------------------------------
// k_enc (32 blocks x 256): C = concat(hidden @ W_enc + b_enc, action)
// ---------------------------------------------------------------------------
__global__ __launch_bounds__(256) void k_enc(
    const float* __restrict__ hidden, const float* __restrict__ action,
    const float* __restrict__ W_enc, const float* __restrict__ b_enc,
    float* __restrict__ C)
{
    __shared__ float Hs[8 * 132];
    __shared__ float We[2048];
    const int mb = blockIdx.x, tid = threadIdx.x;
    {
        int r = tid >> 5, kq = tid & 31;
        *((float4*)&Hs[r * 132 + kq * 4]) =
            *(const float4*)(hidden + (size_t)(mb * 8 + r) * HID + kq * 4);
        float4 a4 = *(const float4*)(action + (size_t)(mb * 8 + r) * HID + kq * 4);
        *((float4*)(C + (size_t)(mb * 8 + r) * DD + 16 + kq * 4)) = a4;
        *((float4*)&We[tid * 4])        = *(const float4*)(W_enc + tid * 4);
        *((float4*)&We[1024 + tid * 4]) = *(const float4*)(W_enc + 1024 + tid * 4);
    }
    __syncthreads();
    if (tid < 128) {
        int r = tid >> 4, o = tid & 15;
        float acc = 0.f;
        #pragma unroll 8
        for (int d = 0; d < HID; ++d) acc += Hs[r * 132 + d] * We[d * 16 + o];
        C[(size_t)(mb * 8 + r) * DD + o] = acc + b_enc[o];
    }
}

// ---------------------------------------------------------------------------
// k_t3 (grid 32x9x3, 256 thr): T_z = C @ Wz + bz   (K=144, split-K 36/wave)
// ---------------------------------------------------------------------------
__global__ __launch_bounds__(256) void k_t3(
    const float* __restrict__ C,
    const float* __restrict__ Wq, const float* __restrict__ bq,
    const float* __restrict__ Wk, const float* __restrict__ bk,
    const float* __restrict__ Wv, const float* __restrict__ bv,
    float* __restrict__ Tq, float* __restrict__ Tk, float* __restrict__ Tv)
{
    __shared__ float sm[2048];               // max(8*148, 2048)
    const int z = blockIdx.z;
    const float* W = (z == 0) ? Wq : (z == 1) ? Wk : Wv;
    const float* b = (z == 0) ? bq : (z == 1) ? bk : bv;
    float*       T = (z == 0) ? Tq : (z == 1) ? Tk : Tv;
    const int rbase = blockIdx.x * 8, cb = blockIdx.y * 64;
    gemm8x64_sk(C + (size_t)rbase * DD, W + cb, b + cb, nullptr, nullptr,
                T + (size_t)rbase * EE + cb, DD, DD, EE, EE, 64,
                threadIdx.x, sm);
}

// ---------------------------------------------------------------------------
// k_qkv3 (grid 32x9x3, 256 thr): {q,k,v} = T_z @ Wiz + biz (K=576, 144/wave)
// ---------------------------------------------------------------------------
__global__ __launch_bounds__(256) void k_qkv3(
    const float* __restrict__ Tq, const float* __restrict__ Tk, const float* __restrict__ Tv,
    const float* __restrict__ Wiq, const float* __restrict__ biq,
    const float* __restrict__ Wik, const float* __restrict__ bik,
    const float* __restrict__ Wiv, const float* __restrict__ biv,
    float* __restrict__ q, float* __restrict__ kb, float* __restrict__ v)
{
    __shared__ float sm[8 * 580];
    const int z = blockIdx.z;
    const float* A = (z == 0) ? Tq  : (z == 1) ? Tk  : Tv;
    const float* W = (z == 0) ? Wiq : (z == 1) ? Wik : Wiv;
    const float* b = (z == 0) ? biq : (z == 1) ? bik : biv;
    float*       o = (z == 0) ? q   : (z == 1) ? kb  : v;
    const int rbase = blockIdx.x * 8, cb = blockIdx.y * 64;
    gemm8x64_sk(A + (size_t)rbase * EE, W + cb, b + cb, nullptr, nullptr,
                o + (size_t)rbase * EE + cb, EE, EE, EE, EE, 64,
                threadIdx.x, sm);
}

// ---------------------------------------------------------------------------
// k_score (grid 32x4x4, 64 thr): S[h][j][k] = (q_j . k_k)/12  for ALL pairs.
// ---------------------------------------------------------------------------
#define DOT4(a, b) ((a).x*(b).x + (a).y*(b).y + (a).z*(b).z + (a).w*(b).w)

__global__ __launch_bounds__(64) void k_score(
    const float* __restrict__ q, const float* __restrict__ kmat,
    float* __restrict__ S)
{
    __shared__ float Aq[8 * 148];
    __shared__ float Bk[64 * 148];
    const int tid = threadIdx.x;
    const int jb = blockIdx.x * 8, kbb = blockIdx.y * 64, h = blockIdx.z;
    const float* Ap = q    + (size_t)jb  * EE + h * HDIM;
    const float* Bp = kmat + (size_t)kbb * EE + h * HDIM;
    for (int idx = tid; idx < 8 * 36; idx += 64) {
        int r = idx / 36, f = idx - r * 36;
        *((float4*)&Aq[r * 148 + f * 4]) = *(const float4*)(Ap + (size_t)r * EE + f * 4);
    }
    for (int idx = tid; idx < 64 * 36; idx += 64) {
        int r = idx / 36, f = idx - r * 36;
        *((float4*)&Bk[r * 148 + f * 4]) = *(const float4*)(Bp + (size_t)r * EE + f * 4);
    }
    __syncthreads();
    const int cg = tid & 15, rg = tid >> 4;
    const int c0 = cg * 4;
    float4 acc0 = {0.f, 0.f, 0.f, 0.f}, acc1 = {0.f, 0.f, 0.f, 0.f};
    const float* A0 = Aq + (rg * 2) * 148;
    const float* A1 = A0 + 148;
    const float* B0 = Bk + (c0 + 0) * 148;
    const float* B1 = Bk + (c0 + 1) * 148;
    const float* B2 = Bk + (c0 + 2) * 148;
    const float* B3 = Bk + (c0 + 3) * 148;
    for (int g = 0; g < 36; ++g) {
        float4 a0 = *((const float4*)(A0 + g * 4));
        float4 a1 = *((const float4*)(A1 + g * 4));
        float4 b0 = *((const float4*)(B0 + g * 4));
        float4 b1 = *((const float4*)(B1 + g * 4));
        float4 b2 = *((const float4*)(B2 + g * 4));
        float4 b3 = *((const float4*)(B3 + g * 4));
        acc0.x += DOT4(a0, b0); acc0.y += DOT4(a0, b1);
        acc0.z += DOT4(a0, b2); acc0.w += DOT4(a0, b3);
        acc1.x += DOT4(a1, b0); acc1.y += DOT4(a1, b1);
        acc1.z += DOT4(a1, b2); acc1.w += DOT4(a1, b3);
    }
    const float SC = 1.0f / 12.0f;
    float* Sp = S + ((size_t)(h * NAG + jb + rg * 2)) * NAG + kbb + c0;
    float4 o0 = { acc0.x * SC, acc0.y * SC, acc0.z * SC, acc0.w * SC };
    float4 o1 = { acc1.x * SC, acc1.y * SC, acc1.z * SC, acc1.w * SC };
    *(float4*)Sp = o0;
    *(float4*)(Sp + NAG) = o1;
}

// ---------------------------------------------------------------------------
// k_agent (grid 256 x 256 thr): neighbor list -> gather S -> softmax ->
// column-sum weights -> ctx = sum w*v.
// ---------------------------------------------------------------------------
__global__ __launch_bounds__(256) void k_agent(
    const int* __restrict__ state, const float* __restrict__ S,
    const float* __restrict__ v,
    float* __restrict__ ctxsum, float* __restrict__ cnt)
{
    __shared__ int lst[NAG];
    __shared__ int cnt_s;
    __shared__ float w4[NH][NAG];
    __shared__ float Sl[NH][CMAX][CMAX + 1];
    const int i = blockIdx.x, tid = threadIdx.x;
    if (tid == 0) cnt_s = 0;
    __syncthreads();
    {
        int xi = state[2 * i], yi = state[2 * i + 1];
        int xj = state[2 * tid], yj = state[2 * tid + 1];
        int dx = xi - xj; if (dx < 0) dx = -dx;
        int dy = yi - yj; if (dy < 0) dy = -dy;
        if (tid > i && dx <= 4 && dy <= 2) {
            int p = atomicAdd(&cnt_s, 1);
            lst[p] = tid;
        }
    }
    __syncthreads();
    const int c = cnt_s;                    // block-uniform
    if (tid == 0) cnt[i] = (float)c;
    if (c == 0) {
        for (int e = tid; e < EE; e += 256) ctxsum[(size_t)i * EE + e] = 0.f;
        return;
    }
    if (c <= CMAX) {
        for (int idx = tid; idx < NH * c * c; idx += 256) {
            int h = idx / (c * c), rem = idx - h * c * c;
            int jj = rem / c, kk = rem - jj * c;
            Sl[h][jj][kk] = S[((size_t)(h * NAG + lst[jj])) * NAG + lst[kk]];
        }
        __syncthreads();
        if (tid < NH * c) {
            int h = tid / c, jj = tid - h * c;
            float m = -1e30f;
            for (int kk = 0; kk < c; ++kk) m = fmaxf(m, Sl[h][jj][kk]);
            float zz = 0.f;
            for (int kk = 0; kk < c; ++kk) {
                float e = __expf(Sl[h][jj][kk] - m);
                Sl[h][jj][kk] = e;
                zz += e;
            }
            float inv = 1.f / fmaxf(zz, 1e-9f);
            for (int kk = 0; kk < c; ++kk) Sl[h][jj][kk] *= inv;
        }
        __syncthreads();
        if (tid < NH * c) {
            int h = tid / c, kk = tid - h * c;
            float s = 0.f;
            for (int jj = 0; jj < c; ++jj) s += Sl[h][jj][kk];
            w4[h][kk] = s;
        }
        __syncthreads();
    } else {
        for (int idx = tid; idx < NH * c; idx += 256) w4[idx / c][idx % c] = 0.f;
        __syncthreads();
        for (int t = tid; t < NH * c; t += 256) {
            int h = t / c, jj = t - h * c;
            const float* Srow = S + ((size_t)(h * NAG + lst[jj])) * NAG;
            float m = -1e30f;
            for (int kk = 0; kk < c; ++kk) m = fmaxf(m, Srow[lst[kk]]);
            float zz = 0.f;
            for (int kk = 0; kk < c; ++kk) zz += __expf(Srow[lst[kk]] - m);
            float inv = 1.f / fmaxf(zz, 1e-9f);
            for (int kk = 0; kk < c; ++kk)
                atomicAdd(&w4[h][kk], __expf(Srow[lst[kk]] - m) * inv);
        }
        __syncthreads();
    }
    for (int e = tid; e < EE; e += 256) {
        int h = e / HDIM;
        float a0 = 0.f, a1 = 0.f;
        int t = 0;
        for (; t + 1 < c; t += 2) {
            a0 += w4[h][t] * v[(size_t)lst[t] * EE + e];
            a1 += w4[h][t + 1] * v[(size_t)lst[t + 1] * EE + e];
        }
        if (t < c) a0 += w4[h][t] * v[(size_t)lst[t] * EE + e];
        ctxsum[(size_t)i * EE + e] = a0 + a1;
    }
}

// ---------------------------------------------------------------------------
// k_g (grid 32x9, 256 thr): g = ctx @ Wo + cnt*bo   (K=576, split-K)
// ---------------------------------------------------------------------------
__global__ __launch_bounds__(256) void k_g(
    const float* __restrict__ ctx, const float* __restrict__ Wo,
    const float* __restrict__ bo, const float* __restrict__ cnt,
    float* __restrict__ g)
{
    __shared__ float sm[8 * 580];
    const int rbase = blockIdx.x * 8, cb = blockIdx.y * 64;
    gemm8x64_sk(ctx + (size_t)rbase * EE, Wo + cb, nullptr, cnt + rbase, bo + cb,
                g + (size_t)rbase * EE + cb, EE, EE, EE, EE, 64,
                threadIdx.x, sm);
}

// ---------------------------------------------------------------------------
// k_h (grid 32x3, 256 thr): hbuf = g @ W_O   (K=576, N=144, split-K)
// ---------------------------------------------------------------------------
__global__ __launch_bounds__(256) void k_h(
    const float* __restrict__ g, const float* __restrict__ W_O,
    float* __restrict__ hbuf)
{
    __shared__ float sm[8 * 580];
    const int rbase = blockIdx.x * 8, cb = blockIdx.y * 64;
    const int nv = DD - cb;                  // 64, 64(80 clipped), 16
    gemm8x64_sk(g + (size_t)rbase * EE, W_O + cb, nullptr, nullptr, nullptr,
                hbuf + (size_t)rbase * DD + cb, EE, EE, DD, DD,
                (nv < 64) ? nv : 64, threadIdx.x, sm);
}

// ---------------------------------------------------------------------------
// k_head (grid 64 x 256): dueling head, one wave per agent.
// ---------------------------------------------------------------------------
__global__ __launch_bounds__(256) void k_head(
    const float* __restrict__ hbuf,
    const float* __restrict__ W_val, const float* __restrict__ b_val,
    const float* __restrict__ W_adv, const float* __restrict__ b_adv,
    float* __restrict__ out)
{
    const int ag = blockIdx.x * 4 + (threadIdx.x >> 6);
    const int lane = threadIdx.x & 63;
    const float* hp = hbuf + (size_t)ag * DD;
    float h0 = hp[lane], h1 = hp[lane + 64];
    float h2 = (lane < 16) ? hp[lane + 128] : 0.f;
    float red[6];
    for (int o = 0; o < 6; ++o) {
        float p;
        if (o < 5) {
            p = h0 * W_adv[lane * ACT + o] + h1 * W_adv[(lane + 64) * ACT + o];
            if (lane < 16) p += h2 * W_adv[(lane + 128) * ACT + o];
        } else {
            p = h0 * W_val[lane] + h1 * W_val[lane + 64];
            if (lane < 16) p += h2 * W_val[lane + 128];
        }
        for (int off = 32; off; off >>= 1) p += __shfl_xor(p, off);
        red[o] = p;
    }
    if (lane == 0) {
        float a[ACT], mean = 0.f;
        for (int o = 0; o < ACT; ++o) { a[o] = red[o] + b_adv[o]; mean += a[o]; }
        mean *= (1.0f / ACT);
        float V = red[5] + b_val[0];
        for (int o = 0; o < ACT; ++o) out[ag * ACT + o] = V + a[o] - mean;
    }
}

// ---------------------------------------------------------------------------
extern "C" void kernel_launch(void* const* d_in, const int* in_sizes, int n_in,
                              void* d_out, int out_size, void* d_ws, size_t ws_size,
                              hipStream_t stream)
{
    const float* hidden = (const float*)d_in[0];
    const float* action = (const float*)d_in[1];
    const int*   state  = (const int*)d_in[2];
    const float* W_enc  = (const float*)d_in[3];
    const float* b_enc  = (const float*)d_in[4];
    const float* Wq     = (const float*)d_in[5];
    const float* bq     = (const float*)d_in[6];
    const float* Wk     = (const float*)d_in[7];
    const float* bk     = (const float*)d_in[8];
    const float* Wv     = (const float*)d_in[9];
    const float* bv     = (const float*)d_in[10];
    const float* Wiq    = (const float*)d_in[11];
    const float* biq    = (const float*)d_in[12];
    const float* Wik    = (const float*)d_in[13];
    const float* bik    = (const float*)d_in[14];
    const float* Wiv    = (const float*)d_in[15];
    const float* biv    = (const float*)d_in[16];
    const float* Wo     = (const float*)d_in[17];
    const float* bo     = (const float*)d_in[18];
    const float* W_O    = (const float*)d_in[19];
    const float* W_val  = (const float*)d_in[20];
    const float* b_val  = (const float*)d_in[21];
    const float* W_adv  = (const float*)d_in[22];
    const float* b_adv  = (const float*)d_in[23];
    float* outp = (float*)d_out;

    float* ws = (float*)d_ws;
    float* C    = ws;                        // 256*144   = 36864
    float* Tq   = C    + NAG * DD;           // 256*576   = 147456 each
    float* Tk   = Tq   + NAG * EE;
    float* Tv   = Tk   + NAG * EE;
    float* q    = Tv   + NAG * EE;
    float* kb   = q    + NAG * EE;
    float* v    = kb   + NAG * EE;
    float* S    = v    + NAG * EE;           // 4*256*256 = 262144
    float* ctx  = S    + NH * NAG * NAG;
    float* g    = ctx  + NAG * EE;
    float* hbuf = g    + NAG * EE;           // 256*144
    float* cnt  = hbuf + NAG * DD;           // 256
    // total ~6.1 MB

    k_enc<<<32, 256, 0, stream>>>(hidden, action, W_enc, b_enc, C);
    k_t3<<<dim3(32, 9, 3), 256, 0, stream>>>(C, Wq, bq, Wk, bk, Wv, bv, Tq, Tk, Tv);
    k_qkv3<<<dim3(32, 9, 3), 256, 0, stream>>>(Tq, Tk, Tv, Wiq, biq, Wik, bik,
                                               Wiv, biv, q, kb, v);
    k_score<<<dim3(32, 4, 4), 64, 0, stream>>>(q, kb, S);
    k_agent<<<NAG, 256, 0, stream>>>(state, S, v, ctx, cnt);
    k_g<<<dim3(32, 9), 256, 0, stream>>>(ctx, Wo, bo, cnt, g);
    k_h<<<dim3(32, 3), 256, 0, stream>>>(g, W_O, hbuf);
    k_head<<<64, 256, 0, stream>>>(hbuf, W_val, b_val, W_adv, b_adv, outp);
}